// Round 7
// baseline (315.249 us; speedup 1.0000x reference)
//
#include <hip/hip_runtime.h>

// Problem constants
#define BB 16
#define NL 256
#define RR 24
#define LL 32
#define NN (NL*NL)        // 65536
#define BNN (BB*NN)       // 1048576
#define TT 64             // FW tile
#define NBLK 4            // 256/64

// Output layout (float32), reference return order.
#define O_TDT 0
#define O_RT  16
#define O_TAT 32
#define O_TD  96
#define O_UNS 112
#define O_TTR 128
#define O_TT  144
#define O_ND  1048720

static __device__ __forceinline__ void atomicMinF(float* a, float v){
    atomicMin((unsigned int*)a, __float_as_uint(v));  // ok for non-negative floats
}

// ---------------- init: dist = INF (float4), accumulators = 0 ----------------
__global__ __launch_bounds__(1024) void k_init(float4* __restrict__ dist4, float* __restrict__ acc){
    int idx = blockIdx.x*1024 + threadIdx.x;
    float inf = __builtin_huge_valf();
    dist4[idx] = make_float4(inf, inf, inf, inf);
    if (blockIdx.x == 0 && threadIdx.x < 256) acc[threadIdx.x] = 0.f;
}

// ---------------- route edges: one wave per (b,r) ----------------
__global__ void k_routes(const float* __restrict__ dtm, const int* __restrict__ routes,
                         float* __restrict__ dist, float* __restrict__ acc){
    int br = blockIdx.x; int b = br / RR, r = br % RR;
    int lane = threadIdx.x;
    __shared__ int   s[LL];
    __shared__ float lf[LL], lr[LL], cf[LL], cr[LL];
    if (lane < LL) s[lane] = routes[(b*RR + r)*LL + lane];
    __syncthreads();
    if (lane < LL-1){
        int a0 = s[lane], a1 = s[lane+1];
        const float* dt = dtm + b*NN;
        lf[lane] = dt[a0*NL + a1] + 60.0f;   // MEAN_STOP_TIME_S
        lr[lane] = dt[a1*NL + a0] + 60.0f;
    }
    __syncthreads();
    if (lane == 0){
        float af = 0.f, ar = 0.f;
        cf[0] = 0.f; cr[0] = 0.f;
        for (int l = 0; l < LL-1; l++){
            af += lf[l]; ar += lr[l];
            cf[l+1] = af; cr[l+1] = ar;
        }
        atomicAdd(&acc[b*16 + 1], af + ar);  // total_route_time
    }
    __syncthreads();
    for (int p = lane; p < LL*LL; p += 64){
        int i = p >> 5, j = p & 31;
        if (j > i){
            atomicMinF(&dist[b*NN + s[i]*NL + s[j]], cf[j] - cf[i]); // fwd
            atomicMinF(&dist[b*NN + s[j]*NL + s[i]], cr[j] - cr[i]); // rev
        }
    }
}

// ---------------- one full FW round in a single dispatch -----------------------
// dst(ti,tj) = min(D0, C0 (x) K* (x) B0), K* = in-LDS closure of src(kb,kb),
// C0 = src(ti,kb), B0 = src(kb,tj). Valid for ALL tiles (K* idempotent, 0-diag).
// src/dst double-buffered -> no intra-dispatch races. 256 blocks x 1024 thr.
// dofix (kb==0): FW-init transform on every src read; src hops never read.
__global__ __launch_bounds__(1024) void k_fw_round(
        const float* __restrict__ srcD, const float* __restrict__ srcH,
        float* __restrict__ dstD, float* __restrict__ dstH, int kb, int dofix){
    int b  = blockIdx.y;
    int m  = blockIdx.x;
    int ti = m >> 2, tj = m & 3;
    int t = threadIdx.x;
    int row = t >> 4, c4 = (t & 15)*4;     // this thread's 1x4 slice
    __shared__ float KD[TT][TT], KH[TT][TT];   // diag tile -> K*; later C0
    __shared__ float BD[TT][TT], BH[TT][TT];   // B0; later M = K* (x) B0
    const float* Kg  = srcD + b*NN + kb*TT*(NL+1);
    const float* KgH = srcH + b*NN + kb*TT*(NL+1);
    const float* Bg  = srcD + b*NN + kb*TT*NL + tj*TT;
    const float* BgH = srcH + b*NN + kb*TT*NL + tj*TT;
    const float* Cg  = srcD + b*NN + ti*TT*NL + kb*TT;
    const float* CgH = srcH + b*NN + ti*TT*NL + kb*TT;
    const float* Dg  = srcD + b*NN + ti*TT*NL + tj*TT;
    const float* DgH = srcH + b*NN + ti*TT*NL + tj*TT;

    // prefetch C0, D0 slices into registers (used after closure)
    float cdv[4], chv[4], d0[4], h0[4];
    {
        float4 c = *(const float4*)(Cg + row*NL + c4);
        cdv[0]=c.x; cdv[1]=c.y; cdv[2]=c.z; cdv[3]=c.w;
        float4 dv = *(const float4*)(Dg + row*NL + c4);
        d0[0]=dv.x; d0[1]=dv.y; d0[2]=dv.z; d0[3]=dv.w;
        if (dofix){
            #pragma unroll
            for (int e = 0; e < 4; e++){
                int gi = ti*TT + row;
                int gjC = kb*TT + c4 + e, gjD = tj*TT + c4 + e;
                chv[e] = (gi != gjC && cdv[e] < 1e37f) ? 1.f : 0.f;
                if (gi == gjC) cdv[e] = 0.f;
                h0[e] = (gi != gjD && d0[e] < 1e37f) ? 1.f : 0.f;
                if (gi == gjD) d0[e] = 0.f;
            }
        } else {
            float4 ch4 = *(const float4*)(CgH + row*NL + c4);
            chv[0]=ch4.x; chv[1]=ch4.y; chv[2]=ch4.z; chv[3]=ch4.w;
            float4 h4 = *(const float4*)(DgH + row*NL + c4);
            h0[0]=h4.x; h0[1]=h4.y; h0[2]=h4.z; h0[3]=h4.w;
        }
    }
    // stage K and B0 into LDS
    {
        float4 v = *(const float4*)(Kg + row*NL + c4);
        float kd[4] = {v.x,v.y,v.z,v.w}, kh[4];
        float4 w = *(const float4*)(Bg + row*NL + c4);
        float bd[4] = {w.x,w.y,w.z,w.w}, bh[4];
        if (dofix){
            #pragma unroll
            for (int e = 0; e < 4; e++){
                int col = c4 + e;
                kh[e] = (row != col && kd[e] < 1e37f) ? 1.f : 0.f;
                if (row == col) kd[e] = 0.f;
                int gi = kb*TT + row, gj = tj*TT + col;
                bh[e] = (gi != gj && bd[e] < 1e37f) ? 1.f : 0.f;
                if (gi == gj) bd[e] = 0.f;
            }
        } else {
            float4 q = *(const float4*)(KgH + row*NL + c4);
            kh[0]=q.x; kh[1]=q.y; kh[2]=q.z; kh[3]=q.w;
            float4 r = *(const float4*)(BgH + row*NL + c4);
            bh[0]=r.x; bh[1]=r.y; bh[2]=r.z; bh[3]=r.w;
        }
        #pragma unroll
        for (int e = 0; e < 4; e++){
            KD[row][c4+e] = kd[e]; KH[row][c4+e] = kh[e];
            BD[row][c4+e] = bd[e]; BH[row][c4+e] = bh[e];
        }
    }
    __syncthreads();

    // ---- in-LDS hierarchical closure of K (sub-tile 16, 4 sub-rounds) ----
    for (int skb = 0; skb < 4; skb++){
        int s0 = skb*16;
        // p1': wave 0 closes 16x16 diag sub-tile via shfl (no barriers)
        if (t < 64){
            int i = t >> 2, jg = t & 3;
            float md[4], mh[4];
            #pragma unroll
            for (int c = 0; c < 4; c++){
                md[c] = KD[s0+i][s0+4*jg+c];
                mh[c] = KH[s0+i][s0+4*jg+c];
            }
            #pragma unroll
            for (int k = 0; k < 16; k++){
                float rd[4], rh[4];
                #pragma unroll
                for (int c = 0; c < 4; c++){
                    rd[c] = __shfl(md[c], (k<<2)|jg);
                    rh[c] = __shfl(mh[c], (k<<2)|jg);
                }
                float cd = __shfl(md[k&3], (i<<2)|(k>>2));
                float ch = __shfl(mh[k&3], (i<<2)|(k>>2));
                #pragma unroll
                for (int c = 0; c < 4; c++){
                    float alt = cd + rd[c];
                    if (alt < md[c]){ md[c] = alt; mh[c] = ch + rh[c]; }
                }
            }
            #pragma unroll
            for (int c = 0; c < 4; c++){
                KD[s0+i][s0+4*jg+c] = md[c];
                KH[s0+i][s0+4*jg+c] = mh[c];
            }
        }
        __syncthreads();
        // p2': row strip + col strip, one element of each per thread
        int rr = s0 + (t >> 6);
        int ca = t & 63;
        int cb = s0 + (t & 15);
        float rsd = KD[rr][ca],  rsh = KH[rr][ca];
        float csd = KD[row][cb], csh = KH[row][cb];
        #pragma unroll
        for (int k = 0; k < 16; k++){
            float ad = KD[rr][s0+k],  ah  = KH[rr][s0+k];
            float bd = KD[s0+k][ca],  bh  = KH[s0+k][ca];
            float alt = ad + bd;
            if (alt < rsd){ rsd = alt; rsh = ah + bh; }
            float a2 = KD[row][s0+k], a2h = KH[row][s0+k];
            float b2 = KD[s0+k][cb],  b2h = KH[s0+k][cb];
            float alt2 = a2 + b2;
            if (alt2 < csd){ csd = alt2; csh = a2h + b2h; }
        }
        __syncthreads();
        KD[rr][ca]  = rsd;  KH[rr][ca]  = rsh;
        KD[row][cb] = csd;  KH[row][cb] = csh;
        __syncthreads();
        // p3': full 64x64, 1x4 per thread, barrier-free k loop
        float dd[4], hh[4];
        {
            float4 v = *(float4*)&KD[row][c4];
            float4 w = *(float4*)&KH[row][c4];
            dd[0]=v.x; dd[1]=v.y; dd[2]=v.z; dd[3]=v.w;
            hh[0]=w.x; hh[1]=w.y; hh[2]=w.z; hh[3]=w.w;
        }
        #pragma unroll
        for (int k = 0; k < 16; k++){
            float ad = KD[row][s0+k], ah2 = KH[row][s0+k];
            float4 bv = *(float4*)&KD[s0+k][c4];
            float4 bq = *(float4*)&KH[s0+k][c4];
            float bdv[4]={bv.x,bv.y,bv.z,bv.w}, bhv[4]={bq.x,bq.y,bq.z,bq.w};
            #pragma unroll
            for (int jj = 0; jj < 4; jj++){
                float alt = ad + bdv[jj];
                if (alt < dd[jj]){ dd[jj] = alt; hh[jj] = ah2 + bhv[jj]; }
            }
        }
        __syncthreads();
        *(float4*)&KD[row][c4] = make_float4(dd[0],dd[1],dd[2],dd[3]);
        *(float4*)&KH[row][c4] = make_float4(hh[0],hh[1],hh[2],hh[3]);
        __syncthreads();
    }

    // ---- M = K* (x) B0  (K* has 0 diag -> identity term included) ----
    float md[4] = {__builtin_huge_valf(),__builtin_huge_valf(),__builtin_huge_valf(),__builtin_huge_valf()};
    float mh[4] = {0.f,0.f,0.f,0.f};
    #pragma unroll 8
    for (int v = 0; v < TT; v++){
        float kd = KD[row][v], kh = KH[row][v];
        float4 bv = *(float4*)&BD[v][c4];
        float4 bq = *(float4*)&BH[v][c4];
        float bdv[4]={bv.x,bv.y,bv.z,bv.w}, bhv[4]={bq.x,bq.y,bq.z,bq.w};
        #pragma unroll
        for (int jj = 0; jj < 4; jj++){
            float alt = kd + bdv[jj];
            if (alt < md[jj]){ md[jj] = alt; mh[jj] = kh + bhv[jj]; }
        }
    }
    __syncthreads();   // all K*/B0 reads done
    *(float4*)&BD[row][c4] = make_float4(md[0],md[1],md[2],md[3]);   // M over B0
    *(float4*)&BH[row][c4] = make_float4(mh[0],mh[1],mh[2],mh[3]);
    *(float4*)&KD[row][c4] = make_float4(cdv[0],cdv[1],cdv[2],cdv[3]); // C0 over K*
    *(float4*)&KH[row][c4] = make_float4(chv[0],chv[1],chv[2],chv[3]);
    __syncthreads();

    // ---- dst = min(D0, C0 (x) M) ----
    #pragma unroll 8
    for (int k = 0; k < TT; k++){
        float cd = KD[row][k], ch = KH[row][k];
        float4 bv = *(float4*)&BD[k][c4];
        float4 bq = *(float4*)&BH[k][c4];
        float bdv[4]={bv.x,bv.y,bv.z,bv.w}, bhv[4]={bq.x,bq.y,bq.z,bq.w};
        #pragma unroll
        for (int jj = 0; jj < 4; jj++){
            float alt = cd + bdv[jj];
            if (alt < d0[jj]){ d0[jj] = alt; h0[jj] = ch + bhv[jj]; }
        }
    }
    float* Od = dstD + b*NN + ti*TT*NL + tj*TT;
    float* Oh = dstH + b*NN + ti*TT*NL + tj*TT;
    *(float4*)(Od + row*NL + c4) = make_float4(d0[0],d0[1],d0[2],d0[3]);
    *(float4*)(Oh + row*NL + c4) = make_float4(h0[0],h0[1],h0[2],h0[3]);
}

// ---------------- epilogue: trip_times + reductions + fused finalize ----------
__global__ __launch_bounds__(1024) void k_epi(const float4* __restrict__ dist4,
        const float4* __restrict__ hops4, const float4* __restrict__ demand4,
        float* __restrict__ out, float* __restrict__ acc){
    int b = blockIdx.y;
    int fid = (b*NN >> 2) + blockIdx.x*1024 + threadIdx.x;   // float4 index
    float4 dv = dist4[fid], hv = hops4[fid], mv = demand4[fid];
    float ds[4] = {dv.x,dv.y,dv.z,dv.w};
    float hs[4] = {hv.x,hv.y,hv.z,hv.w};
    float ms[4] = {mv.x,mv.y,mv.z,mv.w};
    float s0=0,s1=0,s2=0,s3=0,s4=0,s5=0,s6=0,s7=0,s8=0;
    float tts[4];
    #pragma unroll
    for (int e = 0; e < 4; e++){
        float d = ds[e], h = hs[e], dm = ms[e];
        bool np = !(d < 1e37f);
        float pl = np ? 0.f : h + 1.f;
        float tr = (pl == 0.f) ? 0.f : pl - 2.f;
        float tt = np ? 0.f : d + tr*300.f;   // AVG_TRANSFER_WAIT_TIME_S
        tts[e] = tt;
        s0 += dm*tt;
        s1 += dm*tr;
        s2 += np ? dm : 0.f;
        s3 += dm;
        s4 += (np && dm > 0.f) ? 1.f : 0.f;
        s5 += (tr == 0.f) ? dm : 0.f;
        s6 += (tr == 1.f) ? dm : 0.f;
        s7 += (tr == 2.f) ? dm : 0.f;
        s8 += (tr > 2.f) ? dm : 0.f;
    }
    ((float4*)(out + O_TT))[fid] = make_float4(tts[0],tts[1],tts[2],tts[3]);
    #define RED(x) { x += __shfl_down(x,32); x += __shfl_down(x,16); x += __shfl_down(x,8); \
                     x += __shfl_down(x,4);  x += __shfl_down(x,2);  x += __shfl_down(x,1); }
    RED(s0) RED(s1) RED(s2) RED(s3) RED(s4) RED(s5) RED(s6) RED(s7) RED(s8)
    __shared__ float red[16][9];
    int w = threadIdx.x >> 6;
    if ((threadIdx.x & 63) == 0){
        red[w][0]=s0; red[w][1]=s1; red[w][2]=s2; red[w][3]=s3; red[w][4]=s4;
        red[w][5]=s5; red[w][6]=s6; red[w][7]=s7; red[w][8]=s8;
    }
    __syncthreads();
    if (threadIdx.x < 9){
        float v = 0.f;
        #pragma unroll
        for (int ww = 0; ww < 16; ww++) v += red[ww][threadIdx.x];
        // acc slots: 0 tdt, 1 rt, 2 ttrans, 3 uns, 4 tdem, 5 ndis, 6 b0, 7 b1, 8 b2, 9 bun
        int slot = (threadIdx.x == 0) ? 0 : threadIdx.x + 1;
        atomicAdd(&acc[b*16 + slot], v);
    }
    __syncthreads();
    __shared__ int isLast;
    if (threadIdx.x == 0){
        unsigned prev = atomicAdd((unsigned int*)(acc + 255), 1u);
        isLast = (prev == 255u) ? 1 : 0;   // 16x16 = 256 blocks
    }
    __syncthreads();
    if (isLast && threadIdx.x < BB){
        int bb = threadIdx.x;
        float a[10];
        #pragma unroll
        for (int s = 0; s < 10; s++) a[s] = atomicAdd(&acc[bb*16 + s], 0.f);  // coherent read
        out[O_TDT + bb] = a[0];
        out[O_RT  + bb] = a[1];
        out[O_TAT + 4*bb + 0] = a[6];
        out[O_TAT + 4*bb + 1] = a[7];
        out[O_TAT + 4*bb + 2] = a[8];
        out[O_TAT + 4*bb + 3] = a[9] + a[3];
        out[O_TD  + bb] = a[4];
        out[O_UNS + bb] = a[3];
        out[O_TTR + bb] = a[2];
        out[O_ND  + bb] = a[5];
    }
}

extern "C" void kernel_launch(void* const* d_in, const int* in_sizes, int n_in,
                              void* d_out, int out_size, void* d_ws, size_t ws_size,
                              hipStream_t stream){
    (void)in_sizes; (void)n_in; (void)out_size; (void)ws_size;
    const float* dtm    = (const float*)d_in[0];
    const float* demand = (const float*)d_in[1];
    const int*   routes = (const int*)d_in[2];
    float* out   = (float*)d_out;
    float* distA = (float*)d_ws;            // buf0 D
    float* hopsA = distA + BNN;             // buf0 H
    float* distB = hopsA + BNN;             // buf1 D
    float* hopsB = distB + BNN;             // buf1 H
    float* acc   = hopsB + BNN;             // 256 floats (incl. counter at [255])

    k_init  <<<BNN/4096, 1024, 0, stream>>>((float4*)distA, acc);
    k_routes<<<BB*RR,      64, 0, stream>>>(dtm, routes, distA, acc);
    // 4 rounds, double-buffered: 0: A->B, 1: B->A, 2: A->B, 3: B->A (ends in A)
    k_fw_round<<<dim3(16,BB), 1024, 0, stream>>>(distA, hopsA, distB, hopsB, 0, 1);
    k_fw_round<<<dim3(16,BB), 1024, 0, stream>>>(distB, hopsB, distA, hopsA, 1, 0);
    k_fw_round<<<dim3(16,BB), 1024, 0, stream>>>(distA, hopsA, distB, hopsB, 2, 0);
    k_fw_round<<<dim3(16,BB), 1024, 0, stream>>>(distB, hopsB, distA, hopsA, 3, 0);
    k_epi<<<dim3(16,BB), 1024, 0, stream>>>((const float4*)distA, (const float4*)hopsA,
                                            (const float4*)demand, out, acc);
}